// Round 1
// baseline (449.357 us; speedup 1.0000x reference)
//
#include <hip/hip_runtime.h>
#include <hip/hip_bf16.h>

typedef unsigned short ushort_t;
using short8 = __attribute__((ext_vector_type(8))) short;
using f32x4  = __attribute__((ext_vector_type(4))) float;

constexpr int B_ = 4;
constexpr int T_ = 1024;
constexpr int E_ = 2048;
constexpr int H_ = 32;
constexpr int D_ = 64;
constexpr float GAMMA_  = -12.0f / 1024.0f;   // -0.01171875
constexpr float ONE_MG_ = 1.0f - GAMMA_;      //  1.01171875

__device__ __forceinline__ ushort_t f2bf(float f) {
  union { float f; unsigned int i; } x; x.f = f;
  unsigned int u = x.i;
  u += 0x7fffu + ((u >> 16) & 1u);   // round-to-nearest-even
  return (ushort_t)(u >> 16);
}

// Fused fp32->bf16 convert for x + Wq + Wk + Wv + Wo (one dispatch).
__global__ __launch_bounds__(256) void f2bf_multi(
    const float* __restrict__ x,
    const float* __restrict__ Wq, const float* __restrict__ Wk,
    const float* __restrict__ Wv, const float* __restrict__ Wo,
    ushort_t* __restrict__ xb,
    ushort_t* __restrict__ wqb, ushort_t* __restrict__ wkb,
    ushort_t* __restrict__ wvb, ushort_t* __restrict__ wob) {
  const int i = blockIdx.x * 256 + threadIdx.x;   // float4 index, < 6291456
  const float* src; ushort_t* dst; int off;
  if (i < 2097152)      { src = x;  dst = xb;  off = i; }
  else if (i < 3145728) { src = Wq; dst = wqb; off = i - 2097152; }
  else if (i < 4194304) { src = Wk; dst = wkb; off = i - 3145728; }
  else if (i < 5242880) { src = Wv; dst = wvb; off = i - 4194304; }
  else                  { src = Wo; dst = wob; off = i - 5242880; }
  const float4 f = ((const float4*)src)[off];
  ushort4 u; u.x = f2bf(f.x); u.y = f2bf(f.y); u.z = f2bf(f.z); u.w = f2bf(f.w);
  ((ushort4*)dst)[off] = u;
}

__device__ __forceinline__ void gl_lds16(const ushort_t* g, ushort_t* l) {
  __builtin_amdgcn_global_load_lds(
      (const __attribute__((address_space(1))) void*)g,
      (__attribute__((address_space(3))) void*)l, 16, 0, 0);
}

// ===========================================================================
// 256x256 / BK=64 / 8-wave / 8-phase GEMM core (m201-style template).
// LDS [buf][A=0,B=1][half][128 rows x 64 cols bf16], linear-dest staging with
// inverse-swizzled global source; read-side swizzle byte ^= (row&7)<<4.
// Per tile t (4 phases, serpentine quadrants (0,0)(0,1)(1,1)(1,0)):
//   p0: ds A0(8)+B0(4); stage B0(t+1); bar; MFMA q(0,0); bar
//   p1: ds B1(4);       stage A0(t+2); bar; MFMA q(0,1); bar
//   p2: ds A1(8);       stage B1(t+2); bar; MFMA q(1,1); bar
//   p3: ds B0(4);       stage A1(t+2); bar; MFMA q(1,0); vmcnt(6); bar
// Invariants (hand-verified): every stage issues >=1 phase after the region's
// last ds_read; the single vmcnt(6) at p3 forces exactly tile t+1's 4 halves
// (issued 4-7 phases earlier); tail drains with vmcnt(0) at t==30.
// ===========================================================================

__device__ __forceinline__ void stage_half(
    const ushort_t* __restrict__ g, int grow0, int k0,
    ushort_t* l, int wid, int lane) {
  // wave-uniform LDS dest + per-lane pre-swizzled global source (m173).
  const int rl = lane >> 3;                 // row-within-8 of this lane
  const int c7 = (lane & 7) ^ rl;           // swizzled 16B chunk in the row
#pragma unroll
  for (int q = 0; q < 2; q++) {
    const ushort_t* src =
        g + (size_t)(grow0 + (q * 8 + wid) * 8 + rl) * 2048 + k0 + c7 * 8;
    gl_lds16(src, l + (q * 8 + wid) * 512);
  }
}

__device__ __forceinline__ void ld_a(short8 (&a)[8], const ushort_t* base,
                                     int wm, int l15, int sw0, int sw1) {
#pragma unroll
  for (int m = 0; m < 4; m++) {
    const ushort_t* p = base + (wm * 64 + m * 16 + l15) * 64;
    a[m * 2 + 0] = *(const short8*)(p + sw0);
    a[m * 2 + 1] = *(const short8*)(p + sw1);
  }
}

__device__ __forceinline__ void ld_b(short8 (&b)[4], const ushort_t* base,
                                     int wn, int l15, int sw0, int sw1) {
#pragma unroll
  for (int n = 0; n < 2; n++) {
    const ushort_t* p = base + (wn * 32 + n * 16 + l15) * 64;
    b[n * 2 + 0] = *(const short8*)(p + sw0);
    b[n * 2 + 1] = *(const short8*)(p + sw1);
  }
}

template <int QM, int QN>
__device__ __forceinline__ void mfma_phase(f32x4 (&acc)[8][4],
                                           const short8 (&a)[8],
                                           const short8 (&bfr)[4]) {
#pragma unroll
  for (int m = 0; m < 4; m++)
#pragma unroll
    for (int n = 0; n < 2; n++)
#pragma unroll
      for (int kc = 0; kc < 2; kc++)
        acc[QM * 4 + m][QN * 2 + n] = __builtin_amdgcn_mfma_f32_16x16x32_bf16(
            a[m * 2 + kc], bfr[n * 2 + kc], acc[QM * 4 + m][QN * 2 + n],
            0, 0, 0);
}

#define GFENCE asm volatile("" ::: "memory")

__device__ __forceinline__ void gemm256_core(
    const ushort_t* __restrict__ Ag, const ushort_t* __restrict__ Bg,
    const int row0, const int col0,
    ushort_t (&lds)[2][2][2][8192], f32x4 (&acc)[8][4]) {
  const int tid = threadIdx.x;
  const int wid = tid >> 6, lane = tid & 63;
  const int wm = wid >> 2, wn = wid & 3;        // 2 x 4 wave grid
  const int l15 = lane & 15, quad = lane >> 4;
  const int sw0 = (quad * 8) ^ ((l15 & 7) << 3);        // swizzled elem offs
  const int sw1 = (32 + quad * 8) ^ ((l15 & 7) << 3);

#pragma unroll
  for (int i = 0; i < 8; i++)
#pragma unroll
    for (int j = 0; j < 4; j++) acc[i][j] = (f32x4){0.f, 0.f, 0.f, 0.f};

  short8 a[8], bfr[4];

  // prologue: A0(0) B1(0) A1(0) B0(0) A0(1) B1(1) A1(1)  (14 loads)
  stage_half(Ag, row0,       0,  &lds[0][0][0][0], wid, lane);
  stage_half(Bg, col0 + 128, 0,  &lds[0][1][1][0], wid, lane);
  stage_half(Ag, row0 + 128, 0,  &lds[0][0][1][0], wid, lane);
  stage_half(Bg, col0,       0,  &lds[0][1][0][0], wid, lane);
  stage_half(Ag, row0,       64, &lds[1][0][0][0], wid, lane);
  stage_half(Bg, col0 + 128, 64, &lds[1][1][1][0], wid, lane);
  stage_half(Ag, row0 + 128, 64, &lds[1][0][1][0], wid, lane);
  asm volatile("s_waitcnt vmcnt(6)" ::: "memory");   // tile 0 fully landed
  __builtin_amdgcn_s_barrier();
  GFENCE;

  for (int t = 0; t < 32; ++t) {
    const int buf = t & 1;
    const int kf = (t + 2) * 64;
    // ---- p0: quadrant (0,0)
    ld_a(a, &lds[buf][0][0][0], wm, l15, sw0, sw1);
    ld_b(bfr, &lds[buf][1][0][0], wn, l15, sw0, sw1);
    if (t + 1 < 32)
      stage_half(Bg, col0, (t + 1) * 64, &lds[buf ^ 1][1][0][0], wid, lane);
    GFENCE; __builtin_amdgcn_s_barrier(); GFENCE;
    __builtin_amdgcn_s_setprio(1);
    mfma_phase<0, 0>(acc, a, bfr);
    __builtin_amdgcn_s_setprio(0);
    GFENCE; __builtin_amdgcn_s_barrier(); GFENCE;
    // ---- p1: quadrant (0,1)
    ld_b(bfr, &lds[buf][1][1][0], wn, l15, sw0, sw1);
    if (t + 2 < 32)
      stage_half(Ag, row0, kf, &lds[buf][0][0][0], wid, lane);
    GFENCE; __builtin_amdgcn_s_barrier(); GFENCE;
    __builtin_amdgcn_s_setprio(1);
    mfma_phase<0, 1>(acc, a, bfr);
    __builtin_amdgcn_s_setprio(0);
    GFENCE; __builtin_amdgcn_s_barrier(); GFENCE;
    // ---- p2: quadrant (1,1)
    ld_a(a, &lds[buf][0][1][0], wm, l15, sw0, sw1);
    if (t + 2 < 32)
      stage_half(Bg, col0 + 128, kf, &lds[buf][1][1][0], wid, lane);
    GFENCE; __builtin_amdgcn_s_barrier(); GFENCE;
    __builtin_amdgcn_s_setprio(1);
    mfma_phase<1, 1>(acc, a, bfr);
    __builtin_amdgcn_s_setprio(0);
    GFENCE; __builtin_amdgcn_s_barrier(); GFENCE;
    // ---- p3: quadrant (1,0)
    ld_b(bfr, &lds[buf][1][0][0], wn, l15, sw0, sw1);
    if (t + 2 < 32)
      stage_half(Ag, row0 + 128, kf, &lds[buf][0][1][0], wid, lane);
    GFENCE; __builtin_amdgcn_s_barrier(); GFENCE;
    __builtin_amdgcn_s_setprio(1);
    mfma_phase<1, 0>(acc, a, bfr);
    __builtin_amdgcn_s_setprio(0);
    if (t < 30)       asm volatile("s_waitcnt vmcnt(6)" ::: "memory");
    else if (t == 30) asm volatile("s_waitcnt vmcnt(0)" ::: "memory");
    GFENCE; __builtin_amdgcn_s_barrier(); GFENCE;
  }
}

// ---------------------------------------------------------------------------
// Fused QKV projection: 384 blocks = 3 matrices x (16 M x 8 N) 256^2 tiles.
// ---------------------------------------------------------------------------
__global__ __launch_bounds__(512, 2) void gemm_qkv256(
    const ushort_t* __restrict__ xb,
    const ushort_t* __restrict__ wq, const ushort_t* __restrict__ wk,
    const ushort_t* __restrict__ wv,
    const float* __restrict__ bq, const float* __restrict__ bk,
    const float* __restrict__ bv,
    ushort_t* __restrict__ qout, ushort_t* __restrict__ kout,
    ushort_t* __restrict__ vtout) {
  __shared__ ushort_t lds[2][2][2][8192];       // 128 KiB
  const int g = blockIdx.x;
  const int swz = (g & 7) * 48 + (g >> 3);      // bijective XCD swizzle (384=8*48)
  const int which = swz >> 7;                   // 0=Q 1=K 2=V
  const int rem = swz & 127;
  const int row0 = (rem & 15) * 256;            // consecutive swz walk M: share
  const int col0 = (rem >> 4) * 256;            //   the same weight panel in L2
  const ushort_t* Wt  = (which == 0) ? wq : (which == 1) ? wk : wv;
  const float*   bias = (which == 0) ? bq : (which == 1) ? bk : bv;
  const float    scale = (which == 0) ? 0.125f : 1.0f;
  ushort_t* outp = (which == 0) ? qout : (which == 1) ? kout : vtout;

  f32x4 acc[8][4];
  gemm256_core(xb, Wt, row0, col0, lds, acc);

  const int tid = threadIdx.x;
  const int wid = tid >> 6, lane = tid & 63;
  const int wm = wid >> 2, wn = wid & 3;
  const int l15 = lane & 15, quad = lane >> 4;
#pragma unroll
  for (int ai = 0; ai < 8; ai++) {
    const int r0 = row0 + (ai >> 2) * 128 + wm * 64 + (ai & 3) * 16 + quad * 4;
#pragma unroll
    for (int aj = 0; aj < 4; aj++) {
      const int c = col0 + (aj >> 1) * 128 + wn * 32 + (aj & 1) * 16 + l15;
      const float bia = bias[c];
      const int h = c >> 6, d = c & 63;
#pragma unroll
      for (int reg = 0; reg < 4; reg++) {
        const int rr = r0 + reg;
        const float val = (acc[ai][aj][reg] + bia) * scale;
        const int b = rr >> 10, tt = rr & 1023;
        if (which < 2)
          outp[(((size_t)(b * 32 + h)) * 1024 + tt) * 64 + d] = f2bf(val);
        else
          outp[(((size_t)(b * 32 + h)) * 64 + d) * 1024 + tt] = f2bf(val);
      }
    }
  }
}

// ---------------------------------------------------------------------------
// Output projection: out = attn @ Wo^T + bo, fp32 out. 128 blocks (16M x 8N).
// ---------------------------------------------------------------------------
__global__ __launch_bounds__(512, 2) void gemm_out256(
    const ushort_t* __restrict__ A, const ushort_t* __restrict__ Wt,
    const float* __restrict__ bias, float* __restrict__ Cout) {
  __shared__ ushort_t lds[2][2][2][8192];
  const int g = blockIdx.x;
  const int swz = (g & 7) * 16 + (g >> 3);      // 128 = 8*16
  const int row0 = (swz & 15) * 256;
  const int col0 = (swz >> 4) * 256;

  f32x4 acc[8][4];
  gemm256_core(A, Wt, row0, col0, lds, acc);

  const int tid = threadIdx.x;
  const int wid = tid >> 6, lane = tid & 63;
  const int wm = wid >> 2, wn = wid & 3;
  const int l15 = lane & 15, quad = lane >> 4;
#pragma unroll
  for (int ai = 0; ai < 8; ai++) {
    const int r0 = row0 + (ai >> 2) * 128 + wm * 64 + (ai & 3) * 16 + quad * 4;
#pragma unroll
    for (int aj = 0; aj < 4; aj++) {
      const int c = col0 + (aj >> 1) * 128 + wn * 32 + (aj & 1) * 16 + l15;
      const float bia = bias[c];
#pragma unroll
      for (int reg = 0; reg < 4; reg++)
        Cout[(size_t)(r0 + reg) * 2048 + c] = acc[ai][aj][reg] + bia;
    }
  }
}

// ---------------------------------------------------------------------------
__global__ __launch_bounds__(256) void gates_kernel(
    const float* __restrict__ x, const float* __restrict__ gw,
    const float* __restrict__ gb, float* __restrict__ gates) {
  const int idx = blockIdx.x * 256 + threadIdx.x;  // (b*T+t)*H + h
  const int h = idx & 31;
  const int bt = idx >> 5;
  const float* xp = x + (size_t)bt * E_ + h * D_;
  const float* wp = gw + h * D_;
  float s = 0.f;
#pragma unroll
  for (int d = 0; d < D_; d += 4) {
    const float4 xv = *(const float4*)&xp[d];
    const float4 wv = *(const float4*)&wp[d];
    s = fmaf(xv.x, wv.x, s); s = fmaf(xv.y, wv.y, s);
    s = fmaf(xv.z, wv.z, s); s = fmaf(xv.w, wv.w, s);
  }
  s += gb[h];
  gates[idx] = 1.0f / (1.0f + __expf(-s));
}

// ---------------------------------------------------------------------------
// MFMA flash attention, clipped softmax, fixed m=0 (unchanged this round).
// ---------------------------------------------------------------------------
__global__ __launch_bounds__(256) void attn_mfma(
    const ushort_t* __restrict__ q, const ushort_t* __restrict__ k,
    const ushort_t* __restrict__ vt, const float* __restrict__ gates,
    ushort_t* __restrict__ attn_out) {
  __shared__ ushort_t Kt[64 * 72];       // K tile [s][d], rows padded to 72
  __shared__ ushort_t Vt[64 * 72];       // V^T tile [d][s]
  __shared__ ushort_t Pb[4][16 * 72];    // per-wave P buffer [m][s]

  const int tid = threadIdx.x;
  const int wave = tid >> 6, lane = tid & 63;
  const int l15 = lane & 15, quad = lane >> 4;
  const int bx = blockIdx.x;
  const int qt = 7 - (bx >> 7);          // heavy-first (LPT), 128-row tiles
  const int bh = bx & 127;
  const int h = bh & 31, b = bh >> 5;
  const int t0 = qt * 128;
  const int qt8 = qt * 8;
  const ushort_t* qbase = q  + (size_t)bh * (T_ * D_);
  const ushort_t* kbase = k  + (size_t)bh * (T_ * D_);
  const ushort_t* vbase = vt + (size_t)bh * (D_ * T_);

  short8 qf[2][2];
#pragma unroll
  for (int s = 0; s < 2; s++) {
    const ushort_t* qp =
        qbase + (size_t)(t0 + s * 64 + wave * 16 + l15) * 64 + quad * 8;
    qf[s][0] = *(const short8*)qp;
    qf[s][1] = *(const short8*)(qp + 32);
  }

  const int srow = tid >> 2;             // staging row 0..63
  const int scol = (tid & 3) * 16;       // ushort col 0/16/32/48
  const int nkt = 2 * qt + 2;            // causal K tiles for this Q block

  float l_part[2][4] = {};

  // ---------------- phase 1: denominators (m = 0) ----------------
  for (int kt = 0; kt < nkt; kt++) {
    __syncthreads();
    {
      const ushort_t* kg = &kbase[(size_t)(kt * 64 + srow) * 64 + scol];
      ushort_t* kl = &Kt[srow * 72 + scol];
      *(short8*)kl = *(const short8*)kg;
      *(short8*)(kl + 8) = *(const short8*)(kg + 8);
    }
    __syncthreads();
#pragma unroll
    for (int s = 0; s < 2; s++) {
      const int rb = qt8 + s * 4 + wave;
      if (kt * 4 > rb) continue;         // strip fully masked (wave-uniform)
      f32x4 sc[4];
#pragma unroll
      for (int j = 0; j < 4; j++) {
        const int cb = kt * 4 + j;
        if (cb > rb) {
          sc[j] = (f32x4){-3.0e38f, -3.0e38f, -3.0e38f, -3.0e38f};
          continue;
        }
        const ushort_t* kp = &Kt[(j * 16 + l15) * 72 + quad * 8];
        const short8 kf0 = *(const short8*)kp;
        const short8 kf1 = *(const short8*)(kp + 32);
        f32x4 z = (f32x4){0.f, 0.f, 0.f, 0.f};
        z = __builtin_amdgcn_mfma_f32_16x16x32_bf16(qf[s][0], kf0, z, 0, 0, 0);
        z = __builtin_amdgcn_mfma_f32_16x16x32_bf16(qf[s][1], kf1, z, 0, 0, 0);
        if (cb == rb) {                  // diagonal triangle
#pragma unroll
          for (int r = 0; r < 4; r++)
            if (l15 > quad * 4 + r) z[r] = -3.0e38f;
        }
        sc[j] = z;
      }
#pragma unroll
      for (int r = 0; r < 4; r++)
        l_part[s][r] += __expf(sc[0][r]) + __expf(sc[1][r]) +
                        __expf(sc[2][r]) + __expf(sc[3][r]);
    }
  }

  float c1[2][4];
#pragma unroll
  for (int s = 0; s < 2; s++)
#pragma unroll
    for (int r = 0; r < 4; r++) {
      float e = l_part[s][r];
      e += __shfl_xor(e, 1); e += __shfl_xor(e, 2);
      e += __shfl_xor(e, 4); e += __shfl_xor(e, 8);
      c1[s][r] = ONE_MG_ / e;
    }

  // ---------------- phase 2: clipped P @ V ----------------
  f32x4 acc[2][4];
#pragma unroll
  for (int s = 0; s < 2; s++)
#pragma unroll
    for (int jd = 0; jd < 4; jd++) acc[s][jd] = (f32x4){0.f, 0.f, 0.f, 0.f};

  for (int kt = 0; kt < nkt; kt++) {
    __syncthreads();
    {
      const ushort_t* kg = &kbase[(size_t)(kt * 64 + srow) * 64 + scol];
      ushort_t* kl = &Kt[srow * 72 + scol];
      *(short8*)kl = *(const short8*)kg;
      *(short8*)(kl + 8) = *(const short8*)(kg + 8);
      const ushort_t* vg = &vbase[(size_t)srow * 1024 + kt * 64 + scol];
      ushort_t* vl = &Vt[srow * 72 + scol];
      *(short8*)vl = *(const short8*)vg;
      *(short8*)(vl + 8) = *(const short8*)(vg + 8);
    }
    __syncthreads();
#pragma unroll
    for (int s = 0; s < 2; s++) {
      const int rb = qt8 + s * 4 + wave;
      if (kt * 4 > rb) continue;
      f32x4 sc[4];
#pragma unroll
      for (int j = 0; j < 4; j++) {
        const int cb = kt * 4 + j;
        if (cb > rb) {
          sc[j] = (f32x4){-3.0e38f, -3.0e38f, -3.0e38f, -3.0e38f};
          continue;
        }
        const ushort_t* kp = &Kt[(j * 16 + l15) * 72 + quad * 8];
        const short8 kf0 = *(const short8*)kp;
        const short8 kf1 = *(const short8*)(kp + 32);
        f32x4 z = (f32x4){0.f, 0.f, 0.f, 0.f};
        z = __builtin_amdgcn_mfma_f32_16x16x32_bf16(qf[s][0], kf0, z, 0, 0, 0);
        z = __builtin_amdgcn_mfma_f32_16x16x32_bf16(qf[s][1], kf1, z, 0, 0, 0);
        if (cb == rb) {
#pragma unroll
          for (int r = 0; r < 4; r++)
            if (l15 > quad * 4 + r) z[r] = -3.0e38f;
        }
        sc[j] = z;
      }
      ushort_t* pb = &Pb[wave][0];
#pragma unroll
      for (int j = 0; j < 4; j++) {
#pragma unroll
        for (int r = 0; r < 4; r++) {
          float p = fmaf(c1[s][r], __expf(sc[j][r]), GAMMA_);
          p = fminf(fmaxf(p, 0.f), 1.f);
          pb[(quad * 4 + r) * 72 + j * 16 + l15] = f2bf(p);
        }
      }
      const short8 pf0 = *(const short8*)&pb[l15 * 72 + quad * 8];
      const short8 pf1 = *(const short8*)&pb[l15 * 72 + 32 + quad * 8];
#pragma unroll
      for (int jd = 0; jd < 4; jd++) {
        const ushort_t* vp = &Vt[(jd * 16 + l15) * 72 + quad * 8];
        const short8 vf0 = *(const short8*)vp;
        const short8 vf1 = *(const short8*)(vp + 32);
        acc[s][jd] =
            __builtin_amdgcn_mfma_f32_16x16x32_bf16(pf0, vf0, acc[s][jd], 0, 0, 0);
        acc[s][jd] =
            __builtin_amdgcn_mfma_f32_16x16x32_bf16(pf1, vf1, acc[s][jd], 0, 0, 0);
      }
    }
  }

  // epilogue: gate, write bf16 [B,T,E]
#pragma unroll
  for (int s = 0; s < 2; s++) {
#pragma unroll
    for (int r = 0; r < 4; r++) {
      const int t = t0 + s * 64 + wave * 16 + quad * 4 + r;
      const float g = gates[((size_t)b * T_ + t) * H_ + h];
      ushort_t* op = attn_out + ((size_t)b * T_ + t) * E_ + h * 64;
#pragma unroll
      for (int jd = 0; jd < 4; jd++)
        op[jd * 16 + l15] = f2bf(acc[s][jd][r] * g);
    }
  }
}

// ---------------------------------------------------------------------------
extern "C" void kernel_launch(void* const* d_in, const int* in_sizes, int n_in,
                              void* d_out, int out_size, void* d_ws, size_t ws_size,
                              hipStream_t stream) {
  (void)in_sizes; (void)n_in; (void)out_size; (void)ws_size;
  const float* x  = (const float*)d_in[0];
  // d_in[1] = attention_mask (deterministically causal; handled analytically)
  const float* Wq = (const float*)d_in[2];
  const float* bq = (const float*)d_in[3];
  const float* Wk = (const float*)d_in[4];
  const float* bk = (const float*)d_in[5];
  const float* Wv = (const float*)d_in[6];
  const float* bv = (const float*)d_in[7];
  const float* Wo = (const float*)d_in[8];
  const float* bo = (const float*)d_in[9];
  const float* gw = (const float*)d_in[10];
  const float* gb = (const float*)d_in[11];
  float* out = (float*)d_out;

  char* W = (char*)d_ws;
  ushort_t* xb  = (ushort_t*)(W + 0);          // x bf16       16 MB
  ushort_t* wqb = (ushort_t*)(W + 16777216);   // Wq bf16       8 MB
  ushort_t* wkb = (ushort_t*)(W + 25165824);
  ushort_t* wvb = (ushort_t*)(W + 33554432);
  ushort_t* wob = (ushort_t*)(W + 41943040);
  ushort_t* qb  = (ushort_t*)(W + 50331648);   // q  [B,H,T,D] 16 MB
  ushort_t* kb  = (ushort_t*)(W + 67108864);   // k  [B,H,T,D]
  ushort_t* vtb = (ushort_t*)(W + 83886080);   // V^T [B,H,D,T]
  ushort_t* ab  = (ushort_t*)(W + 100663296);  // attn [B,T,E]
  float*    gts = (float*)(W + 117440512);     // gates fp32

  f2bf_multi<<<24576, 256, 0, stream>>>(x, Wq, Wk, Wv, Wo,
                                        xb, wqb, wkb, wvb, wob);

  // Fused QKV projection: 3 matrices x 16 M-tiles x 8 N-tiles = 384 blocks
  gemm_qkv256<<<384, 512, 0, stream>>>(xb, wqb, wkb, wvb,
                                       bq, bk, bv, qb, kb, vtb);
  gates_kernel<<<512, 256, 0, stream>>>(x, gw, gb, gts);
  attn_mfma<<<1024, 256, 0, stream>>>(qb, kb, vtb, gts, ab);
  gemm_out256<<<128, 512, 0, stream>>>(ab, wob, bo, out);
}

// Round 3
// 444.215 us; speedup vs baseline: 1.0116x; 1.0116x over previous
//
#include <hip/hip_runtime.h>
#include <hip/hip_bf16.h>

typedef unsigned short ushort_t;
using short8 = __attribute__((ext_vector_type(8))) short;
using f32x4  = __attribute__((ext_vector_type(4))) float;

constexpr int B_ = 4;
constexpr int T_ = 1024;
constexpr int E_ = 2048;
constexpr int H_ = 32;
constexpr int D_ = 64;
constexpr float GAMMA_  = -12.0f / 1024.0f;   // -0.01171875
constexpr float ONE_MG_ = 1.0f - GAMMA_;      //  1.01171875

__device__ __forceinline__ ushort_t f2bf(float f) {
  union { float f; unsigned int i; } x; x.f = f;
  unsigned int u = x.i;
  u += 0x7fffu + ((u >> 16) & 1u);   // round-to-nearest-even
  return (ushort_t)(u >> 16);
}

// Fused fp32->bf16 convert for x + Wq + Wk + Wv + Wo (one dispatch).
__global__ __launch_bounds__(256) void f2bf_multi(
    const float* __restrict__ x,
    const float* __restrict__ Wq, const float* __restrict__ Wk,
    const float* __restrict__ Wv, const float* __restrict__ Wo,
    ushort_t* __restrict__ xb,
    ushort_t* __restrict__ wqb, ushort_t* __restrict__ wkb,
    ushort_t* __restrict__ wvb, ushort_t* __restrict__ wob) {
  const int i = blockIdx.x * 256 + threadIdx.x;   // float4 index, < 6291456
  const float* src; ushort_t* dst; int off;
  if (i < 2097152)      { src = x;  dst = xb;  off = i; }
  else if (i < 3145728) { src = Wq; dst = wqb; off = i - 2097152; }
  else if (i < 4194304) { src = Wk; dst = wkb; off = i - 3145728; }
  else if (i < 5242880) { src = Wv; dst = wvb; off = i - 4194304; }
  else                  { src = Wo; dst = wob; off = i - 5242880; }
  const float4 f = ((const float4*)src)[off];
  ushort4 u; u.x = f2bf(f.x); u.y = f2bf(f.y); u.z = f2bf(f.z); u.w = f2bf(f.w);
  ((ushort4*)dst)[off] = u;
}

__device__ __forceinline__ void gl_lds16(const ushort_t* g, ushort_t* l) {
  __builtin_amdgcn_global_load_lds(
      (const __attribute__((address_space(1))) void*)g,
      (__attribute__((address_space(3))) void*)l, 16, 0, 0);
}

__device__ __forceinline__ unsigned ldsoff(const void* p) {
  return (unsigned)(unsigned long long)
      (const __attribute__((address_space(3))) char*)p;
}

// ===========================================================================
// 256x256 / BK=64 / 8-wave / 8-phase GEMM core (m201-style template).
// Inline-asm ds_read_b128 (opaque to the waitcnt pass, so the counted
// vmcnt(6) governs instead of compiler-inserted vmcnt(0) drains), explicit
// lgkmcnt(0) + sched_barrier(0) before each MFMA cluster (rule #18).
// Schedule (WAR/RAW invariants hand-verified, twice):
//   p0: dsA0(8)+dsB0(4); stage B0(t+1); bar; lgkm0; MFMA(0,0); bar
//   p1: dsB1(4);         stage A0(t+2); bar; lgkm0; MFMA(0,1); bar
//   p2: dsA1(8);         stage B1(t+2); bar; lgkm0; MFMA(1,1); bar
//   p3: dsB0(4);         stage A1(t+2); bar; lgkm0; MFMA(1,0); vmcnt(6); bar
// Steady state: 14 outstanding at p3's wait; vmcnt(6) retires the 8 oldest
// = exactly tile t+1's four halves. Uniform control flow -> no deadlock.
// ===========================================================================

__device__ __forceinline__ void stage_half(
    const ushort_t* __restrict__ g, int grow0, int k0,
    ushort_t* l, int wid, int lane) {
  // wave-uniform LDS dest + per-lane pre-swizzled global source (m173).
  const int rl = lane >> 3;                 // row-within-8 of this lane
  const int c7 = (lane & 7) ^ rl;           // swizzled 16B chunk in the row
#pragma unroll
  for (int q = 0; q < 2; q++) {
    const ushort_t* src =
        g + (size_t)(grow0 + (q * 8 + wid) * 8 + rl) * 2048 + k0 + c7 * 8;
    gl_lds16(src, l + (q * 8 + wid) * 512);
  }
}

template <int QM, int QN>
__device__ __forceinline__ void mfma_phase(f32x4 (&acc)[8][4],
                                           const short8 (&a)[8],
                                           const short8 (&b)[4]) {
#pragma unroll
  for (int m = 0; m < 4; m++)
#pragma unroll
    for (int n = 0; n < 2; n++)
#pragma unroll
      for (int kc = 0; kc < 2; kc++)
        acc[QM * 4 + m][QN * 2 + n] = __builtin_amdgcn_mfma_f32_16x16x32_bf16(
            a[m * 2 + kc], b[n * 2 + kc], acc[QM * 4 + m][QN * 2 + n],
            0, 0, 0);
}

#define GFENCE asm volatile("" ::: "memory")
#define DSR(dst, addr, imm) \
  asm volatile("ds_read_b128 %0, %1 offset:" imm : "=&v"(dst) : "v"(addr))
#define LGKM0 do { \
    asm volatile("s_waitcnt lgkmcnt(0)" ::: "memory"); \
    __builtin_amdgcn_sched_barrier(0); \
  } while (0)

// One K-tile = 4 phases. BUF is the LDS double-buffer index (static).
// aA/aB: A-row base addrs (two swizzle chunks); bA/bB: B-row bases.
// Half-1 regions are +16384 bytes (reachable via offset: immediates).
template <int BUF>
__device__ __forceinline__ void tile8(
    int t, const ushort_t* __restrict__ Ag, const ushort_t* __restrict__ Bg,
    int row0, int col0, ushort_t (&lds)[2][2][2][8192], f32x4 (&acc)[8][4],
    int wid, int lane,
    unsigned aA, unsigned aB, unsigned bA, unsigned bB) {
  short8 a[8], b[4];
  const int kf = (t + 2) * 64;
  // ---- p0: quadrant (0,0): A half0 + B half0
  DSR(a[0], aA, "0");     DSR(a[2], aA, "2048");
  DSR(a[4], aA, "4096");  DSR(a[6], aA, "6144");
  DSR(a[1], aB, "0");     DSR(a[3], aB, "2048");
  DSR(a[5], aB, "4096");  DSR(a[7], aB, "6144");
  DSR(b[0], bA, "0");     DSR(b[2], bA, "2048");
  DSR(b[1], bB, "0");     DSR(b[3], bB, "2048");
  if (t + 1 < 32)
    stage_half(Bg, col0, (t + 1) * 64, &lds[BUF ^ 1][1][0][0], wid, lane);
  GFENCE; __builtin_amdgcn_s_barrier();
  LGKM0;
  __builtin_amdgcn_s_setprio(1);
  mfma_phase<0, 0>(acc, a, b);
  __builtin_amdgcn_s_setprio(0);
  GFENCE; __builtin_amdgcn_s_barrier(); GFENCE;
  // ---- p1: quadrant (0,1): B half1 (A regs persist)
  DSR(b[0], bA, "16384"); DSR(b[2], bA, "18432");
  DSR(b[1], bB, "16384"); DSR(b[3], bB, "18432");
  if (t + 2 < 32)
    stage_half(Ag, row0, kf, &lds[BUF][0][0][0], wid, lane);
  GFENCE; __builtin_amdgcn_s_barrier();
  LGKM0;
  __builtin_amdgcn_s_setprio(1);
  mfma_phase<0, 1>(acc, a, b);
  __builtin_amdgcn_s_setprio(0);
  GFENCE; __builtin_amdgcn_s_barrier(); GFENCE;
  // ---- p2: quadrant (1,1): A half1 (B regs persist)
  DSR(a[0], aA, "16384"); DSR(a[2], aA, "18432");
  DSR(a[4], aA, "20480"); DSR(a[6], aA, "22528");
  DSR(a[1], aB, "16384"); DSR(a[3], aB, "18432");
  DSR(a[5], aB, "20480"); DSR(a[7], aB, "22528");
  if (t + 2 < 32)
    stage_half(Bg, col0 + 128, kf, &lds[BUF][1][1][0], wid, lane);
  GFENCE; __builtin_amdgcn_s_barrier();
  LGKM0;
  __builtin_amdgcn_s_setprio(1);
  mfma_phase<1, 1>(acc, a, b);
  __builtin_amdgcn_s_setprio(0);
  GFENCE; __builtin_amdgcn_s_barrier(); GFENCE;
  // ---- p3: quadrant (1,0): B half0 again
  DSR(b[0], bA, "0");     DSR(b[2], bA, "2048");
  DSR(b[1], bB, "0");     DSR(b[3], bB, "2048");
  if (t + 2 < 32)
    stage_half(Ag, row0 + 128, kf, &lds[BUF][0][1][0], wid, lane);
  GFENCE; __builtin_amdgcn_s_barrier();
  LGKM0;
  __builtin_amdgcn_s_setprio(1);
  mfma_phase<1, 0>(acc, a, b);
  __builtin_amdgcn_s_setprio(0);
  if (t < 30)       asm volatile("s_waitcnt vmcnt(6)" ::: "memory");
  else if (t == 30) asm volatile("s_waitcnt vmcnt(0)" ::: "memory");
  GFENCE; __builtin_amdgcn_s_barrier(); GFENCE;
}

__device__ __forceinline__ void gemm256_core(
    const ushort_t* __restrict__ Ag, const ushort_t* __restrict__ Bg,
    const int row0, const int col0,
    ushort_t (&lds)[2][2][2][8192], f32x4 (&acc)[8][4]) {
  const int tid = threadIdx.x;
  const int wid = tid >> 6, lane = tid & 63;
  const int wm = wid >> 2, wn = wid & 3;        // 2 x 4 wave grid
  const int l15 = lane & 15, quad = lane >> 4;
  // swizzled 16B-chunk byte offsets within a 128B LDS row (chunk ^= row&7)
  const unsigned r7   = (unsigned)(l15 & 7);
  const unsigned csw0 = (((unsigned)quad) ^ r7) * 16u;
  const unsigned csw1 = (((unsigned)quad + 4u) ^ r7) * 16u;
  const unsigned aA0 = ldsoff(&lds[0][0][0][(wm * 64 + l15) * 64]) + csw0;
  const unsigned aB0 = ldsoff(&lds[0][0][0][(wm * 64 + l15) * 64]) + csw1;
  const unsigned bA0 = ldsoff(&lds[0][1][0][(wn * 32 + l15) * 64]) + csw0;
  const unsigned bB0 = ldsoff(&lds[0][1][0][(wn * 32 + l15) * 64]) + csw1;
  const unsigned aA1 = aA0 + 65536u, aB1 = aB0 + 65536u;
  const unsigned bA1 = bA0 + 65536u, bB1 = bB0 + 65536u;

#pragma unroll
  for (int i = 0; i < 8; i++)
#pragma unroll
    for (int j = 0; j < 4; j++) acc[i][j] = (f32x4){0.f, 0.f, 0.f, 0.f};

  // prologue: A0(0) B1(0) A1(0) B0(0) A0(1) B1(1) A1(1)  (14 loads)
  stage_half(Ag, row0,       0,  &lds[0][0][0][0], wid, lane);
  stage_half(Bg, col0 + 128, 0,  &lds[0][1][1][0], wid, lane);
  stage_half(Ag, row0 + 128, 0,  &lds[0][0][1][0], wid, lane);
  stage_half(Bg, col0,       0,  &lds[0][1][0][0], wid, lane);
  stage_half(Ag, row0,       64, &lds[1][0][0][0], wid, lane);
  stage_half(Bg, col0 + 128, 64, &lds[1][1][1][0], wid, lane);
  stage_half(Ag, row0 + 128, 64, &lds[1][0][1][0], wid, lane);
  asm volatile("s_waitcnt vmcnt(6)" ::: "memory");   // tile 0 fully landed
  __builtin_amdgcn_s_barrier();
  GFENCE;

  for (int i = 0; i < 16; ++i) {
    tile8<0>(2 * i,     Ag, Bg, row0, col0, lds, acc, wid, lane,
             aA0, aB0, bA0, bB0);
    tile8<1>(2 * i + 1, Ag, Bg, row0, col0, lds, acc, wid, lane,
             aA1, aB1, bA1, bB1);
  }
}

// ---------------------------------------------------------------------------
// Fused QKV projection: 384 blocks = 3 matrices x (16 M x 8 N) 256^2 tiles.
// ---------------------------------------------------------------------------
__global__ __launch_bounds__(512, 2) void gemm_qkv256(
    const ushort_t* __restrict__ xb,
    const ushort_t* __restrict__ wq, const ushort_t* __restrict__ wk,
    const ushort_t* __restrict__ wv,
    const float* __restrict__ bq, const float* __restrict__ bk,
    const float* __restrict__ bv,
    ushort_t* __restrict__ qout, ushort_t* __restrict__ kout,
    ushort_t* __restrict__ vtout) {
  __shared__ ushort_t lds[2][2][2][8192];       // 128 KiB
  const int g = blockIdx.x;
  const int swz = (g & 7) * 48 + (g >> 3);      // bijective XCD swizzle (384=8*48)
  const int which = swz >> 7;                   // 0=Q 1=K 2=V
  const int rem = swz & 127;
  const int row0 = (rem & 15) * 256;            // consecutive swz walk M: share
  const int col0 = (rem >> 4) * 256;            //   the same weight panel in L2
  const ushort_t* Wt  = (which == 0) ? wq : (which == 1) ? wk : wv;
  const float*   bias = (which == 0) ? bq : (which == 1) ? bk : bv;
  const float    scale = (which == 0) ? 0.125f : 1.0f;
  ushort_t* outp = (which == 0) ? qout : (which == 1) ? kout : vtout;

  f32x4 acc[8][4];
  gemm256_core(xb, Wt, row0, col0, lds, acc);

  const int tid = threadIdx.x;
  const int wid = tid >> 6, lane = tid & 63;
  const int wm = wid >> 2, wn = wid & 3;
  const int l15 = lane & 15, quad = lane >> 4;
#pragma unroll
  for (int ai = 0; ai < 8; ai++) {
    const int r0 = row0 + (ai >> 2) * 128 + wm * 64 + (ai & 3) * 16 + quad * 4;
#pragma unroll
    for (int aj = 0; aj < 4; aj++) {
      const int c = col0 + (aj >> 1) * 128 + wn * 32 + (aj & 1) * 16 + l15;
      const float bia = bias[c];
      const int h = c >> 6, d = c & 63;
#pragma unroll
      for (int reg = 0; reg < 4; reg++) {
        const int rr = r0 + reg;
        const float val = (acc[ai][aj][reg] + bia) * scale;
        const int b = rr >> 10, tt = rr & 1023;
        if (which < 2)
          outp[(((size_t)(b * 32 + h)) * 1024 + tt) * 64 + d] = f2bf(val);
        else
          outp[(((size_t)(b * 32 + h)) * 64 + d) * 1024 + tt] = f2bf(val);
      }
    }
  }
}

// ---------------------------------------------------------------------------
// Output projection: out = attn @ Wo^T + bo, fp32 out. 128 blocks (16M x 8N).
// ---------------------------------------------------------------------------
__global__ __launch_bounds__(512, 2) void gemm_out256(
    const ushort_t* __restrict__ A, const ushort_t* __restrict__ Wt,
    const float* __restrict__ bias, float* __restrict__ Cout) {
  __shared__ ushort_t lds[2][2][2][8192];
  const int g = blockIdx.x;
  const int swz = (g & 7) * 16 + (g >> 3);      // 128 = 8*16
  const int row0 = (swz & 15) * 256;
  const int col0 = (swz >> 4) * 256;

  f32x4 acc[8][4];
  gemm256_core(A, Wt, row0, col0, lds, acc);

  const int tid = threadIdx.x;
  const int wid = tid >> 6, lane = tid & 63;
  const int wm = wid >> 2, wn = wid & 3;
  const int l15 = lane & 15, quad = lane >> 4;
#pragma unroll
  for (int ai = 0; ai < 8; ai++) {
    const int r0 = row0 + (ai >> 2) * 128 + wm * 64 + (ai & 3) * 16 + quad * 4;
#pragma unroll
    for (int aj = 0; aj < 4; aj++) {
      const int c = col0 + (aj >> 1) * 128 + wn * 32 + (aj & 1) * 16 + l15;
      const float bia = bias[c];
#pragma unroll
      for (int reg = 0; reg < 4; reg++)
        Cout[(size_t)(r0 + reg) * 2048 + c] = acc[ai][aj][reg] + bia;
    }
  }
}

// ---------------------------------------------------------------------------
__global__ __launch_bounds__(256) void gates_kernel(
    const float* __restrict__ x, const float* __restrict__ gw,
    const float* __restrict__ gb, float* __restrict__ gates) {
  const int idx = blockIdx.x * 256 + threadIdx.x;  // (b*T+t)*H + h
  const int h = idx & 31;
  const int bt = idx >> 5;
  const float* xp = x + (size_t)bt * E_ + h * D_;
  const float* wp = gw + h * D_;
  float s = 0.f;
#pragma unroll
  for (int d = 0; d < D_; d += 4) {
    const float4 xv = *(const float4*)&xp[d];
    const float4 wv = *(const float4*)&wp[d];
    s = fmaf(xv.x, wv.x, s); s = fmaf(xv.y, wv.y, s);
    s = fmaf(xv.z, wv.z, s); s = fmaf(xv.w, wv.w, s);
  }
  s += gb[h];
  gates[idx] = 1.0f / (1.0f + __expf(-s));
}

// ---------------------------------------------------------------------------
// MFMA flash attention, clipped softmax, fixed m=0 (unchanged this round).
// ---------------------------------------------------------------------------
__global__ __launch_bounds__(256) void attn_mfma(
    const ushort_t* __restrict__ q, const ushort_t* __restrict__ k,
    const ushort_t* __restrict__ vt, const float* __restrict__ gates,
    ushort_t* __restrict__ attn_out) {
  __shared__ ushort_t Kt[64 * 72];       // K tile [s][d], rows padded to 72
  __shared__ ushort_t Vt[64 * 72];       // V^T tile [d][s]
  __shared__ ushort_t Pb[4][16 * 72];    // per-wave P buffer [m][s]

  const int tid = threadIdx.x;
  const int wave = tid >> 6, lane = tid & 63;
  const int l15 = lane & 15, quad = lane >> 4;
  const int bx = blockIdx.x;
  const int qt = 7 - (bx >> 7);          // heavy-first (LPT), 128-row tiles
  const int bh = bx & 127;
  const int h = bh & 31, b = bh >> 5;
  const int t0 = qt * 128;
  const int qt8 = qt * 8;
  const ushort_t* qbase = q  + (size_t)bh * (T_ * D_);
  const ushort_t* kbase = k  + (size_t)bh * (T_ * D_);
  const ushort_t* vbase = vt + (size_t)bh * (D_ * T_);

  short8 qf[2][2];
#pragma unroll
  for (int s = 0; s < 2; s++) {
    const ushort_t* qp =
        qbase + (size_t)(t0 + s * 64 + wave * 16 + l15) * 64 + quad * 8;
    qf[s][0] = *(const short8*)qp;
    qf[s][1] = *(const short8*)(qp + 32);
  }

  const int srow = tid >> 2;             // staging row 0..63
  const int scol = (tid & 3) * 16;       // ushort col 0/16/32/48
  const int nkt = 2 * qt + 2;            // causal K tiles for this Q block

  float l_part[2][4] = {};

  // ---------------- phase 1: denominators (m = 0) ----------------
  for (int kt = 0; kt < nkt; kt++) {
    __syncthreads();
    {
      const ushort_t* kg = &kbase[(size_t)(kt * 64 + srow) * 64 + scol];
      ushort_t* kl = &Kt[srow * 72 + scol];
      *(short8*)kl = *(const short8*)kg;
      *(short8*)(kl + 8) = *(const short8*)(kg + 8);
    }
    __syncthreads();
#pragma unroll
    for (int s = 0; s < 2; s++) {
      const int rb = qt8 + s * 4 + wave;
      if (kt * 4 > rb) continue;         // strip fully masked (wave-uniform)
      f32x4 sc[4];
#pragma unroll
      for (int j = 0; j < 4; j++) {
        const int cb = kt * 4 + j;
        if (cb > rb) {
          sc[j] = (f32x4){-3.0e38f, -3.0e38f, -3.0e38f, -3.0e38f};
          continue;
        }
        const ushort_t* kp = &Kt[(j * 16 + l15) * 72 + quad * 8];
        const short8 kf0 = *(const short8*)kp;
        const short8 kf1 = *(const short8*)(kp + 32);
        f32x4 z = (f32x4){0.f, 0.f, 0.f, 0.f};
        z = __builtin_amdgcn_mfma_f32_16x16x32_bf16(qf[s][0], kf0, z, 0, 0, 0);
        z = __builtin_amdgcn_mfma_f32_16x16x32_bf16(qf[s][1], kf1, z, 0, 0, 0);
        if (cb == rb) {                  // diagonal triangle
#pragma unroll
          for (int r = 0; r < 4; r++)
            if (l15 > quad * 4 + r) z[r] = -3.0e38f;
        }
        sc[j] = z;
      }
#pragma unroll
      for (int r = 0; r < 4; r++)
        l_part[s][r] += __expf(sc[0][r]) + __expf(sc[1][r]) +
                        __expf(sc[2][r]) + __expf(sc[3][r]);
    }
  }

  float c1[2][4];
#pragma unroll
  for (int s = 0; s < 2; s++)
#pragma unroll
    for (int r = 0; r < 4; r++) {
      float e = l_part[s][r];
      e += __shfl_xor(e, 1); e += __shfl_xor(e, 2);
      e += __shfl_xor(e, 4); e += __shfl_xor(e, 8);
      c1[s][r] = ONE_MG_ / e;
    }

  // ---------------- phase 2: clipped P @ V ----------------
  f32x4 acc[2][4];
#pragma unroll
  for (int s = 0; s < 2; s++)
#pragma unroll
    for (int jd = 0; jd < 4; jd++) acc[s][jd] = (f32x4){0.f, 0.f, 0.f, 0.f};

  for (int kt = 0; kt < nkt; kt++) {
    __syncthreads();
    {
      const ushort_t* kg = &kbase[(size_t)(kt * 64 + srow) * 64 + scol];
      ushort_t* kl = &Kt[srow * 72 + scol];
      *(short8*)kl = *(const short8*)kg;
      *(short8*)(kl + 8) = *(const short8*)(kg + 8);
      const ushort_t* vg = &vbase[(size_t)srow * 1024 + kt * 64 + scol];
      ushort_t* vl = &Vt[srow * 72 + scol];
      *(short8*)vl = *(const short8*)vg;
      *(short8*)(vl + 8) = *(const short8*)(vg + 8);
    }
    __syncthreads();
#pragma unroll
    for (int s = 0; s < 2; s++) {
      const int rb = qt8 + s * 4 + wave;
      if (kt * 4 > rb) continue;
      f32x4 sc[4];
#pragma unroll
      for (int j = 0; j < 4; j++) {
        const int cb = kt * 4 + j;
        if (cb > rb) {
          sc[j] = (f32x4){-3.0e38f, -3.0e38f, -3.0e38f, -3.0e38f};
          continue;
        }
        const ushort_t* kp = &Kt[(j * 16 + l15) * 72 + quad * 8];
        const short8 kf0 = *(const short8*)kp;
        const short8 kf1 = *(const short8*)(kp + 32);
        f32x4 z = (f32x4){0.f, 0.f, 0.f, 0.f};
        z = __builtin_amdgcn_mfma_f32_16x16x32_bf16(qf[s][0], kf0, z, 0, 0, 0);
        z = __builtin_amdgcn_mfma_f32_16x16x32_bf16(qf[s][1], kf1, z, 0, 0, 0);
        if (cb == rb) {
#pragma unroll
          for (int r = 0; r < 4; r++)
            if (l15 > quad * 4 + r) z[r] = -3.0e38f;
        }
        sc[j] = z;
      }
      ushort_t* pb = &Pb[wave][0];
#pragma unroll
      for (int j = 0; j < 4; j++) {
#pragma unroll
        for (int r = 0; r < 4; r++) {
          float p = fmaf(c1[s][r], __expf(sc[j][r]), GAMMA_);
          p = fminf(fmaxf(p, 0.f), 1.f);
          pb[(quad * 4 + r) * 72 + j * 16 + l15] = f2bf(p);
        }
      }
      const short8 pf0 = *(const short8*)&pb[l15 * 72 + quad * 8];
      const short8 pf1 = *(const short8*)&pb[l15 * 72 + 32 + quad * 8];
#pragma unroll
      for (int jd = 0; jd < 4; jd++) {
        const ushort_t* vp = &Vt[(jd * 16 + l15) * 72 + quad * 8];
        const short8 vf0 = *(const short8*)vp;
        const short8 vf1 = *(const short8*)(vp + 32);
        acc[s][jd] =
            __builtin_amdgcn_mfma_f32_16x16x32_bf16(pf0, vf0, acc[s][jd], 0, 0, 0);
        acc[s][jd] =
            __builtin_amdgcn_mfma_f32_16x16x32_bf16(pf1, vf1, acc[s][jd], 0, 0, 0);
      }
    }
  }

  // epilogue: gate, write bf16 [B,T,E]
#pragma unroll
  for (int s = 0; s < 2; s++) {
#pragma unroll
    for (int r = 0; r < 4; r++) {
      const int t = t0 + s * 64 + wave * 16 + quad * 4 + r;
      const float g = gates[((size_t)b * T_ + t) * H_ + h];
      ushort_t* op = attn_out + ((size_t)b * T_ + t) * E_ + h * 64;
#pragma unroll
      for (int jd = 0; jd < 4; jd++)
        op[jd * 16 + l15] = f2bf(acc[s][jd][r] * g);
    }
  }
}

// ---------------------------------------------------------------------------
extern "C" void kernel_launch(void* const* d_in, const int* in_sizes, int n_in,
                              void* d_out, int out_size, void* d_ws, size_t ws_size,
                              hipStream_t stream) {
  (void)in_sizes; (void)n_in; (void)out_size; (void)ws_size;
  const float* x  = (const float*)d_in[0];
  // d_in[1] = attention_mask (deterministically causal; handled analytically)
  const float* Wq = (const float*)d_in[2];
  const float* bq = (const float*)d_in[3];
  const float* Wk = (const float*)d_in[4];
  const float* bk = (const float*)d_in[5];
  const float* Wv = (const float*)d_in[6];
  const float* bv = (const float*)d_in[7];
  const float* Wo = (const float*)d_in[8];
  const float* bo = (const float*)d_in[9];
  const float* gw = (const float*)d_in[10];
  const float* gb = (const float*)d_in[11];
  float* out = (float*)d_out;

  char* W = (char*)d_ws;
  ushort_t* xb  = (ushort_t*)(W + 0);          // x bf16       16 MB
  ushort_t* wqb = (ushort_t*)(W + 16777216);   // Wq bf16       8 MB
  ushort_t* wkb = (ushort_t*)(W + 25165824);
  ushort_t* wvb = (ushort_t*)(W + 33554432);
  ushort_t* wob = (ushort_t*)(W + 41943040);
  ushort_t* qb  = (ushort_t*)(W + 50331648);   // q  [B,H,T,D] 16 MB
  ushort_t* kb  = (ushort_t*)(W + 67108864);   // k  [B,H,T,D]
  ushort_t* vtb = (ushort_t*)(W + 83886080);   // V^T [B,H,D,T]
  ushort_t* ab  = (ushort_t*)(W + 100663296);  // attn [B,T,E]
  float*    gts = (float*)(W + 117440512);     // gates fp32

  f2bf_multi<<<24576, 256, 0, stream>>>(x, Wq, Wk, Wv, Wo,
                                        xb, wqb, wkb, wvb, wob);

  // Fused QKV projection: 3 matrices x 16 M-tiles x 8 N-tiles = 384 blocks
  gemm_qkv256<<<384, 512, 0, stream>>>(xb, wqb, wkb, wvb,
                                       bq, bk, bv, qb, kb, vtb);
  gates_kernel<<<512, 256, 0, stream>>>(x, gw, gb, gts);
  attn_mfma<<<1024, 256, 0, stream>>>(qb, kb, vtb, gts, ab);
  gemm_out256<<<128, 512, 0, stream>>>(ab, wob, bo, out);
}